// Round 2
// 157.491 us; speedup vs baseline: 1.0539x; 1.0539x over previous
//
#include <hip/hip_runtime.h>

// RBF classifier: out = exp(-(||x-c||^2) * exp(-2*log_sigma)) @ W^T + b
// B=16384, D=784, C=2048, OUT=10. All fp32 in/out.
//
// R3b: identical to R3 (256x256 / 8-wave / 4-phase-per-K-tile, HK-style raw
// s_barrier + counted vmcnt(2), double-buffered 128KiB LDS, setprio around
// MFMA clusters, preps fused into one launch). R3's bench died at container
// level with no kernel evidence; audit found no hang mechanism (uniform
// barriers, consistent vmcnt FIFO, "memory"-clobbered waits guarding every
// cross-buffer hazard) -> resubmitting unchanged to disambiguate infra flake
// from schedule-induced hang.

#define B_ROWS 16384
#define D_DIM  784
#define C_DIM  2048
#define NOUT   10
#define KPAD   832
#define BK     64
#define NT     13            // KPAD / BK

typedef __attribute__((ext_vector_type(8))) __bf16 bf16x8;
typedef __attribute__((ext_vector_type(4))) float  f32x4;
typedef __attribute__((ext_vector_type(4))) unsigned short ushort4v;

__device__ __forceinline__ unsigned short f2bf(float f) {
  union { float f; unsigned int u; } v; v.f = f;
  unsigned int u = v.u;
  return (unsigned short)((u + 0x7fffu + ((u >> 16) & 1u)) >> 16);  // RNE
}

// async global->LDS, 16B per lane. LDS dest = wave-uniform base + lane*16.
__device__ __forceinline__ void async16(const unsigned short* g, unsigned short* l) {
  __builtin_amdgcn_global_load_lds((const __attribute__((address_space(1))) void*)g,
                                   (__attribute__((address_space(3))) void*)l,
                                   16, 0, 0);
}

// fp32 row -> bf16 row (padded to KPAD with zeros) + sum of squares.
// one WAVE per row; no LDS, no syncthreads.
__device__ __forceinline__ void conv_row(const float* __restrict__ src,
                                         unsigned short* __restrict__ dst,
                                         float* __restrict__ sq, int row, int lane) {
  const float* s = src + (size_t)row * D_DIM;
  unsigned short* d = dst + (size_t)row * KPAD;
  float acc = 0.f;
#pragma unroll
  for (int c = 0; c < 4; ++c) {
    const int ch = lane + c * 64;           // ushort4 chunk index, 208 total
    if (ch < 196) {
      const float4 v = ((const float4*)s)[ch];
      ushort4v o; o.x = f2bf(v.x); o.y = f2bf(v.y); o.z = f2bf(v.z); o.w = f2bf(v.w);
      *(ushort4v*)(d + ch * 4) = o;
      acc += v.x * v.x + v.y * v.y + v.z * v.z + v.w * v.w;
    } else if (ch < 208) {
      ushort4v z = {0, 0, 0, 0};
      *(ushort4v*)(d + ch * 4) = z;
    }
  }
#pragma unroll
  for (int off = 32; off > 0; off >>= 1) acc += __shfl_down(acc, off);
  if (lane == 0) sq[row] = acc;
}

// one launch for all preprocessing: x rows | centre rows | bias/Wb/scale.
__global__ __launch_bounds__(256) void prep_all(
    const float* __restrict__ x, const float* __restrict__ cen,
    const float* __restrict__ ls, const float* __restrict__ W,
    const float* __restrict__ bias,
    unsigned short* __restrict__ xb, unsigned short* __restrict__ cb,
    unsigned short* __restrict__ wb,
    float* __restrict__ x2, float* __restrict__ c2, float* __restrict__ sc,
    float* __restrict__ out) {
  const int bx = blockIdx.x;
  if (bx < B_ROWS / 4) {
    conv_row(x, xb, x2, bx * 4 + (threadIdx.x >> 6), threadIdx.x & 63);
  } else if (bx < B_ROWS / 4 + C_DIM / 4) {
    conv_row(cen, cb, c2, (bx - B_ROWS / 4) * 4 + (threadIdx.x >> 6), threadIdx.x & 63);
  } else {
    const int i = (bx - (B_ROWS / 4 + C_DIM / 4)) * 256 + threadIdx.x;
    if (i < B_ROWS * NOUT) out[i] = bias[i % NOUT];
    const int j = i - B_ROWS * NOUT;
    if (j >= 0 && j < 16 * C_DIM)
      wb[j] = ((j >> 11) < NOUT) ? f2bf(W[(j >> 11) * C_DIM + (j & 2047)]) : (unsigned short)0;
    const int k = j - 16 * C_DIM;
    if (k >= 0 && k < C_DIM) sc[k] = __expf(-2.f * ls[k]);
  }
}

// --- main fused kernel: 256x256 tile over (B,C), BK=64, 8 waves 2x4.
// LDS: 2 x (A 256x64 + B 256x64) bf16 stage buffers (128KiB), overlaid in
// the epilogue by Ph[256][264] bf16 (132KiB); +3KiB f32 vectors on top.
__global__ __launch_bounds__(512, 2) void rbf_main(
    const unsigned short* __restrict__ xb, const unsigned short* __restrict__ cb,
    const unsigned short* __restrict__ wb,
    const float* __restrict__ x2, const float* __restrict__ c2,
    const float* __restrict__ scale, float* __restrict__ out) {
  __shared__ __align__(16) char smem[138240];   // 135168 Ph + 3*1024 vectors
  unsigned short* Ph = (unsigned short*)smem;   // 256 x 264 shorts
  float* x2s = (float*)(smem + 135168);
  float* c2s = (float*)(smem + 136192);
  float* scs = (float*)(smem + 137216);

  const int tid  = threadIdx.x;
  const int w    = tid >> 6;
  const int lane = tid & 63;
  const int q    = lane >> 4;
  const int l16  = lane & 15;
  const int swz  = l16 & 7;
  const int brow = blockIdx.x * 256;
  const int bcol = blockIdx.y * 256;
  const int wr   = (w >> 2) * 128;   // wave row offset: 0 or 128
  const int wc   = (w & 3) * 64;     // wave col offset: 0,64,128,192

  // per-tile vectors (x2 for rows, c2/scale for cols)
  if (tid < 256) { c2s[tid] = c2[bcol + tid]; scs[tid] = scale[bcol + tid]; }
  else           { x2s[tid - 256] = x2[brow + tid - 256]; }

  // staging: thread t covers (row = r*64 + t/8, k-chunk (t&7) ^ (row&7)) per
  // issue r (8KB each; A tile = 4 issues, B tile = 4 issues). XOR swizzle is
  // applied on the GLOBAL source (LDS dest stays linear, required by
  // global_load_lds), undone on the read side.
  const int srow = tid >> 3;                       // 0..63
  const int skc  = (tid & 7) ^ (srow & 7);
  const unsigned short* gA = xb + (size_t)(brow + srow) * KPAD + skc * 8;
  const unsigned short* gB = cb + (size_t)(bcol + srow) * KPAD + skc * 8;
  const int ldst = w * 512;                        // lds: + r*4096, +lane*8 implicit

#define STG_A(P, K0, R) async16(gA + (size_t)(R) * 64 * KPAD + (K0), (P) + (R) * 4096 + ldst)
#define STG_B(P, K0, R) async16(gB + (size_t)(R) * 64 * KPAD + (K0), (P) + (R) * 4096 + ldst)

  // prologue: stage tile 0, order B0,B1,B2,B3,A0,A2,A1,A3; retire all but the
  // last two (A1,A3 = rows 64-127/192-255, first needed at phase 2 of t=0).
  {
    unsigned short* A0 = (unsigned short*)smem;
    unsigned short* B0 = (unsigned short*)(smem + 32768);
    STG_B(B0, 0, 0); STG_B(B0, 0, 1); STG_B(B0, 0, 2); STG_B(B0, 0, 3);
    STG_A(A0, 0, 0); STG_A(A0, 0, 2); STG_A(A0, 0, 1); STG_A(A0, 0, 3);
  }
  asm volatile("s_waitcnt vmcnt(2) lgkmcnt(0)" ::: "memory");
  __builtin_amdgcn_s_barrier();

  f32x4 acc[8][4] = {};

#define LD_A(IH, KS)                                                        \
  _Pragma("unroll")                                                         \
  for (int ii = 0; ii < 4; ++ii)                                            \
    af[ii] = *(const bf16x8*)&As[(wr + (IH) * 64 + ii * 16 + l16) * 64 +    \
                                 ((((KS) * 4 + q) ^ swz) << 3)];
#define LD_B(KS)                                                            \
  _Pragma("unroll")                                                         \
  for (int j = 0; j < 4; ++j)                                               \
    bfr[j] = *(const bf16x8*)&Bs[(wc + j * 16 + l16) * 64 +                 \
                                 ((((KS) * 4 + q) ^ swz) << 3)];
#define MFMA16(IOFF)                                                        \
  __builtin_amdgcn_s_setprio(1);                                            \
  _Pragma("unroll")                                                         \
  for (int ii = 0; ii < 4; ++ii)                                            \
    _Pragma("unroll")                                                       \
    for (int j = 0; j < 4; ++j)                                             \
      acc[(IOFF) + ii][j] = __builtin_amdgcn_mfma_f32_16x16x32_bf16(        \
          af[ii], bfr[j], acc[(IOFF) + ii][j], 0, 0, 0);                    \
  __builtin_amdgcn_s_setprio(0);

  for (int t = 0; t < NT; ++t) {
    char* base_r = smem + (t & 1) * 65536;
    char* base_s = smem + ((t + 1) & 1) * 65536;
    unsigned short* As  = (unsigned short*)base_r;             // 256x64
    unsigned short* Bs  = (unsigned short*)(base_r + 32768);   // 256x64
    unsigned short* Asn = (unsigned short*)base_s;
    unsigned short* Bsn = (unsigned short*)(base_s + 32768);
    const int kn = (t + 1) * BK;
    const bool st = (t < NT - 1);
    bf16x8 af[4], bfr[4];

    // ---- phase 1: ks=0, ih=0 (rows wr..wr+63) ----
    LD_A(0, 0)
    LD_B(0)
    if (st) { STG_B(Bsn, kn, 0); STG_B(Bsn, kn, 1); }
    __builtin_amdgcn_s_barrier();
    MFMA16(0)
    if (st) asm volatile("s_waitcnt vmcnt(2)" ::: "memory");  // tile t A1,A3 landed
    else    asm volatile("s_waitcnt vmcnt(0)" ::: "memory");
    __builtin_amdgcn_s_barrier();

    // ---- phase 2: ks=0, ih=1 (rows wr+64..wr+127), reuse bfr ----
    LD_A(1, 0)
    if (st) { STG_B(Bsn, kn, 2); STG_B(Bsn, kn, 3); }
    __builtin_amdgcn_s_barrier();
    MFMA16(4)
    __builtin_amdgcn_s_barrier();

    // ---- phase 3: ks=1, ih=0 ----
    LD_A(0, 1)
    LD_B(1)
    if (st) { STG_A(Asn, kn, 0); STG_A(Asn, kn, 2); }
    __builtin_amdgcn_s_barrier();
    MFMA16(0)
    __builtin_amdgcn_s_barrier();

    // ---- phase 4: ks=1, ih=1 ----
    LD_A(1, 1)
    if (st) { STG_A(Asn, kn, 1); STG_A(Asn, kn, 3); }
    __builtin_amdgcn_s_barrier();
    MFMA16(4)
    if (st) asm volatile("s_waitcnt vmcnt(2)" ::: "memory");  // tile t+1 B0-3,A0,A2 landed
    __builtin_amdgcn_s_barrier();
  }

  __syncthreads();   // nothing outstanding; fence before Ph overlays stage LDS

  // epilogue 1: d2 -> phi -> Ph (bf16). C/D layout: col=lane&15, row=q*4+r.
#pragma unroll
  for (int i = 0; i < 8; ++i) {
#pragma unroll
    for (int j = 0; j < 4; ++j) {
      const int cl = wc + j * 16 + l16;
      const float c2v = c2s[cl];
      const float sc = scs[cl];
#pragma unroll
      for (int r = 0; r < 4; ++r) {
        const int rl = wr + i * 16 + q * 4 + r;
        float d2 = fmaxf(x2s[rl] + c2v - 2.f * acc[i][j][r], 0.f);
        Ph[rl * 264 + cl] = f2bf(__expf(-d2 * sc));
      }
    }
  }
  __syncthreads();

  // epilogue 2: out_tile(256x10) = Ph(256x256) @ Wb(16-row slice)^T, K=256.
  // wave w handles rows w*32 .. w*32+31 (2 M-frags).
  f32x4 oacc[2] = {};
#pragma unroll
  for (int kk = 0; kk < 8; ++kk) {
    const bf16x8 bw = *(const bf16x8*)&wb[(size_t)l16 * C_DIM + bcol + kk * 32 + q * 8];
#pragma unroll
    for (int mi = 0; mi < 2; ++mi) {
      const bf16x8 ap = *(const bf16x8*)&Ph[(w * 32 + mi * 16 + l16) * 264 + kk * 32 + q * 8];
      oacc[mi] = __builtin_amdgcn_mfma_f32_16x16x32_bf16(ap, bw, oacc[mi], 0, 0, 0);
    }
  }
  if (l16 < NOUT) {
#pragma unroll
    for (int mi = 0; mi < 2; ++mi)
#pragma unroll
      for (int r = 0; r < 4; ++r) {
        const int grow = brow + w * 32 + mi * 16 + q * 4 + r;
        atomicAdd(&out[grow * NOUT + l16], oacc[mi][r]);
      }
  }
#undef STG_A
#undef STG_B
#undef LD_A
#undef LD_B
#undef MFMA16
}

extern "C" void kernel_launch(void* const* d_in, const int* in_sizes, int n_in,
                              void* d_out, int out_size, void* d_ws, size_t ws_size,
                              hipStream_t stream) {
  const float* x    = (const float*)d_in[0];  // (16384,784)
  const float* cen  = (const float*)d_in[1];  // (2048,784)
  const float* ls   = (const float*)d_in[2];  // (2048,)
  const float* W    = (const float*)d_in[3];  // (10,2048)
  const float* bias = (const float*)d_in[4];  // (10,)
  float* out = (float*)d_out;                 // (16384,10)

  unsigned char* ws = (unsigned char*)d_ws;
  unsigned short* xb  = (unsigned short*)(ws);              // 16384*832*2 = 27,262,976
  unsigned short* cbf = (unsigned short*)(ws + 27262976);   //  2048*832*2 =  3,407,872
  unsigned short* wb  = (unsigned short*)(ws + 30670848);   //   16*2048*2 =     65,536
  float* x2 = (float*)(ws + 30736384);                      // 16384*4
  float* c2 = (float*)(ws + 30801920);                      //  2048*4
  float* sc = (float*)(ws + 30810112);                      //  2048*4   (end 30,818,304)

  const int prep_blocks = B_ROWS / 4 + C_DIM / 4 +
                          (B_ROWS * NOUT + 16 * C_DIM + C_DIM + 255) / 256;
  prep_all<<<prep_blocks, 256, 0, stream>>>(x, cen, ls, W, bias, xb, cbf, wb, x2, c2, sc, out);
  rbf_main<<<dim3(B_ROWS / 256, C_DIM / 256), 512, 0, stream>>>(xb, cbf, wb, x2, c2, sc, out);
}